// Round 6
// baseline (4234.138 us; speedup 1.0000x reference)
//
#include <hip/hip_runtime.h>
#include <hip/hip_bf16.h>
#include <math.h>

#define S_LEN 64
#define T_LEN 32
#define BATCH 512
#define IN_DIM 66
#define INP 128         // IN_DIM zero-padded to multiple of 64
#define H_DIM 1024
#define O_DIM 1024
#define H3 3072

typedef __attribute__((ext_vector_type(8))) short short8;
typedef __attribute__((ext_vector_type(4))) float f32x4;
typedef __attribute__((ext_vector_type(4))) unsigned short us4;

__device__ __forceinline__ unsigned short f2b(float f) {
    union { float f; unsigned u; } x; x.f = f;
    unsigned r = x.u + 0x7FFF + ((x.u >> 16) & 1);
    return (unsigned short)(r >> 16);
}
__device__ __forceinline__ float b2f(unsigned short s) {
    union { unsigned u; float f; } x; x.u = ((unsigned)s) << 16;
    return x.f;
}
// async global->LDS, 16B per lane; lds base must be wave-uniform
__device__ __forceinline__ void gll16(const void* g, const void* l) {
    __builtin_amdgcn_global_load_lds(
        (const __attribute__((address_space(1))) unsigned int*)g,
        (__attribute__((address_space(3))) unsigned int*)l, 16, 0, 0);
}

// ---------------------------------------------------------------------------
// MFMA GEMM, bf16: C[M,N] = A@W^T, tile TM x TN. lda/ldw mult of 8, K mult 32.
// flags: 1 bias, 2 add fp32, 4 add bf16, 8 relu, 16 store f32, 32 store bf16
// ---------------------------------------------------------------------------
template<int TM, int TN>
__global__ __launch_bounds__(256) void gemm_k(
    const unsigned short* __restrict__ A, int lda,
    const unsigned short* __restrict__ W, int ldw,
    const float* __restrict__ bias,
    const float* __restrict__ addf, const unsigned short* __restrict__ addb,
    int ldadd,
    float* __restrict__ Cf,
    unsigned short* __restrict__ Cb, int ldc,
    int K, int flags)
{
    constexpr int IF = TM / 16;   // A frags per wave
    constexpr int JF = TN / 64;   // B frags per wave
    constexpr int NW = TN / 4;    // cols per wave
    constexpr int CA = TM * 4;    // 16B chunks in A tile
    constexpr int CW = TN * 4;
    __shared__ __align__(16) unsigned short As[TM * 32];
    __shared__ __align__(16) unsigned short Bs[TN * 32];

    const int bm = blockIdx.y * TM;
    const int bn = blockIdx.x * TN;
    const int t = threadIdx.x;
    const int lane = t & 63;
    const int wv = t >> 6;
    const int ln = lane & 15;
    const int quad = lane >> 4;

    f32x4 acc[IF][JF];
    #pragma unroll
    for (int i = 0; i < IF; i++)
        #pragma unroll
        for (int j = 0; j < JF; j++) {
            f32x4 z = {0.f, 0.f, 0.f, 0.f};
            acc[i][j] = z;
        }

    for (int k0 = 0; k0 < K; k0 += 32) {
        if constexpr (CA >= 256) {
            #pragma unroll
            for (int j = 0; j < CA / 256; j++) {
                int ch = j * 256 + t;
                gll16(A + (size_t)(bm + (ch >> 2)) * lda + k0 + (ch & 3) * 8,
                      (const char*)As + (j * 4 + wv) * 1024);
            }
        } else {
            if (t < CA)
                gll16(A + (size_t)(bm + (t >> 2)) * lda + k0 + (t & 3) * 8,
                      (const char*)As + wv * 1024);
        }
        if constexpr (CW >= 256) {
            #pragma unroll
            for (int j = 0; j < CW / 256; j++) {
                int ch = j * 256 + t;
                gll16(W + (size_t)(bn + (ch >> 2)) * ldw + k0 + (ch & 3) * 8,
                      (const char*)Bs + (j * 4 + wv) * 1024);
            }
        } else {
            if (t < CW)
                gll16(W + (size_t)(bn + (t >> 2)) * ldw + k0 + (t & 3) * 8,
                      (const char*)Bs + wv * 1024);
        }
        __syncthreads();
        short8 af[IF], bf[JF];
        #pragma unroll
        for (int i = 0; i < IF; i++)
            af[i] = *(const short8*)&As[(i * 16 + ln) * 32 + quad * 8];
        #pragma unroll
        for (int j = 0; j < JF; j++)
            bf[j] = *(const short8*)&Bs[(wv * NW + j * 16 + ln) * 32 + quad * 8];
        #pragma unroll
        for (int i = 0; i < IF; i++)
            #pragma unroll
            for (int j = 0; j < JF; j++)
                acc[i][j] = __builtin_amdgcn_mfma_f32_16x16x32_bf16(
                    af[i], bf[j], acc[i][j], 0, 0, 0);
        __syncthreads();
    }

    #pragma unroll
    for (int i = 0; i < IF; i++) {
        #pragma unroll
        for (int j = 0; j < JF; j++) {
            #pragma unroll
            for (int r = 0; r < 4; r++) {
                int m = bm + i * 16 + quad * 4 + r;
                int n = bn + wv * NW + j * 16 + ln;
                float v = acc[i][j][r];
                if (flags & 1) v += bias[n];
                if (flags & 2) v += addf[(size_t)m * ldadd + n];
                if (flags & 4) v += b2f(addb[(size_t)m * ldadd + n]);
                if (flags & 8) v = fmaxf(v, 0.f);
                if (flags & 16) Cf[(size_t)m * ldc + n] = v;
                if (flags & 32) Cb[(size_t)m * ldc + n] = f2b(v);
            }
        }
    }
}

// ---------------------------------------------------------------------------
// No-LDS GRU GEMM phase: fragments loaded straight to VGPRs (each frag is
// 16 contiguous bytes/lane -> one global_load_dwordx4), 2-stage register
// pipeline, zero barriers. K must be a multiple of 128.
// ---------------------------------------------------------------------------
__device__ __forceinline__ void gru_mma(
    short8 a0, short8 a1, short8 b0, short8 b1, short8 b2,
    f32x4 (&accR)[2], f32x4 (&accZ)[2], f32x4 (&accN)[2])
{
    accR[0] = __builtin_amdgcn_mfma_f32_16x16x32_bf16(a0, b0, accR[0], 0, 0, 0);
    accR[1] = __builtin_amdgcn_mfma_f32_16x16x32_bf16(a1, b0, accR[1], 0, 0, 0);
    accZ[0] = __builtin_amdgcn_mfma_f32_16x16x32_bf16(a0, b1, accZ[0], 0, 0, 0);
    accZ[1] = __builtin_amdgcn_mfma_f32_16x16x32_bf16(a1, b1, accZ[1], 0, 0, 0);
    accN[0] = __builtin_amdgcn_mfma_f32_16x16x32_bf16(a0, b2, accN[0], 0, 0, 0);
    accN[1] = __builtin_amdgcn_mfma_f32_16x16x32_bf16(a1, b2, accN[1], 0, 0, 0);
}

__device__ __forceinline__ void gru_phase(
    const unsigned short* __restrict__ A, int lda,
    const unsigned short* __restrict__ W, int ldw, int K,
    int ar0, int ar1, int br0, int br1, int br2, int ko,
    f32x4 (&accR)[2], f32x4 (&accZ)[2], f32x4 (&accN)[2])
{
    const unsigned short* pa0 = A + (size_t)ar0 * lda + ko;
    const unsigned short* pa1 = A + (size_t)ar1 * lda + ko;
    const unsigned short* pw0 = W + (size_t)br0 * ldw + ko;
    const unsigned short* pw1 = W + (size_t)br1 * ldw + ko;
    const unsigned short* pw2 = W + (size_t)br2 * ldw + ko;

#define GRU_LD(va0, va1, vb0, vb1, vb2, kk)            \
    va0 = *(const short8*)(pa0 + (kk));                \
    va1 = *(const short8*)(pa1 + (kk));                \
    vb0 = *(const short8*)(pw0 + (kk));                \
    vb1 = *(const short8*)(pw1 + (kk));                \
    vb2 = *(const short8*)(pw2 + (kk));

    short8 a0A, a1A, b0A, b1A, b2A;
    short8 a0B, a1B, b0B, b1B, b2B;
    short8 a0T, a1T, b0T, b1T, b2T;
    GRU_LD(a0A, a1A, b0A, b1A, b2A, 0)
    GRU_LD(a0B, a1B, b0B, b1B, b2B, 32)
    int k = 0;
    for (; k < K - 64; k += 64) {
        GRU_LD(a0T, a1T, b0T, b1T, b2T, k + 64)
        gru_mma(a0A, a1A, b0A, b1A, b2A, accR, accZ, accN);
        a0A = a0T; a1A = a1T; b0A = b0T; b1A = b1T; b2A = b2T;
        GRU_LD(a0T, a1T, b0T, b1T, b2T, k + 96)
        gru_mma(a0B, a1B, b0B, b1B, b2B, accR, accZ, accN);
        a0B = a0T; a1B = a1T; b0B = b0T; b1B = b1T; b2B = b2T;
    }
    gru_mma(a0A, a1A, b0A, b1A, b2A, accR, accZ, accN);
    gru_mma(a0B, a1B, b0B, b1B, b2B, accR, accZ, accN);
#undef GRU_LD
}

// ---------------------------------------------------------------------------
// Fused GRU step, no LDS: h' = GRU(x, h). Tile 64 batch x 32 cols/gate,
// 4 waves: wave = (batch-half, col-half) -> per wave 32 batch x 16 cols of
// each of the 3 gates. Grid (1024/32, 512/64) = (32, 8) = 256 blocks.
// K0 and 1024 must be multiples of 128.
// ---------------------------------------------------------------------------
__global__ __launch_bounds__(256) void gru_gemm(
    const unsigned short* __restrict__ A0, int lda0,
    const unsigned short* __restrict__ W0, int ldw0, int K0,
    const unsigned short* __restrict__ A1,   // hb_in [512,1024]
    const unsigned short* __restrict__ W1,   // Whh   [3072,1024]
    const float* __restrict__ bih, const float* __restrict__ bhh,
    const float* __restrict__ hf_in, float* __restrict__ hf_out,
    unsigned short* __restrict__ hb_out, unsigned short* __restrict__ slot)
{
    const int t = threadIdx.x;
    const int w = t >> 6;
    const int lane = t & 63;
    const int ln = lane & 15;
    const int quad = lane >> 4;
    const int bm = blockIdx.y * 64 + (w >> 1) * 32;   // wave's batch base
    const int cg = blockIdx.x * 32 + (w & 1) * 16;    // wave's col-in-gate base
    const int ar0 = bm + ln, ar1 = bm + 16 + ln;
    const int br0 = cg + ln;
    const int br1 = H_DIM + cg + ln;
    const int br2 = 2 * H_DIM + cg + ln;
    const int ko = quad * 8;

    f32x4 accR[2], accZ[2], accN0[2], accN1[2];
    #pragma unroll
    for (int i = 0; i < 2; i++) {
        f32x4 z = {0.f, 0.f, 0.f, 0.f};
        accR[i] = z; accZ[i] = z; accN0[i] = z; accN1[i] = z;
    }

    gru_phase(A0, lda0, W0, ldw0, K0, ar0, ar1, br0, br1, br2, ko,
              accR, accZ, accN0);
    gru_phase(A1, H_DIM, W1, H_DIM, H_DIM, ar0, ar1, br0, br1, br2, ko,
              accR, accZ, accN1);

    const int n = cg + ln;
    const float br = bih[n] + bhh[n];
    const float bz = bih[H_DIM + n] + bhh[H_DIM + n];
    const float bi_n = bih[2 * H_DIM + n];
    const float bh_n = bhh[2 * H_DIM + n];
    #pragma unroll
    for (int i = 0; i < 2; i++) {
        #pragma unroll
        for (int r = 0; r < 4; r++) {
            const int m = bm + i * 16 + quad * 4 + r;
            const size_t idx = (size_t)m * H_DIM + n;
            float rg = 1.f / (1.f + __expf(-(accR[i][r] + br)));
            float zg = 1.f / (1.f + __expf(-(accZ[i][r] + bz)));
            float av = accN0[i][r] + bi_n + rg * (accN1[i][r] + bh_n);
            float e2 = __expf(-2.f * fabsf(av));
            float th = (1.f - e2) / (1.f + e2);
            th = av < 0.f ? -th : th;
            float o = (1.f - zg) * th + zg * hf_in[idx];
            hf_out[idx] = o;
            unsigned short ob = f2b(o);
            hb_out[idx] = ob;
            if (slot) slot[idx] = ob;
        }
    }
}

// ---------------------------------------------------------------------------
// Fused attention: one block per batch row. scores = h.wAhT + attnx (bf16),
// softmax over 64, then ctx[b,:] = sum_l aw[l] * enc[l,b,:]. 512 blocks.
// ---------------------------------------------------------------------------
__global__ __launch_bounds__(256) void attn_ctx(
    const unsigned short* __restrict__ hb,     // [512,1024] bf16
    const unsigned short* __restrict__ wAhT,   // [1024][64] bf16 (k-major)
    const unsigned short* __restrict__ attnx_t,// [512,64] bf16 (incl bias)
    const unsigned short* __restrict__ encb,   // [64,512,1024] bf16
    unsigned short* __restrict__ ctx)          // [512,1024] bf16
{
    __shared__ float hf[H_DIM];
    __shared__ float part[4][S_LEN];
    __shared__ float awl[S_LEN];
    const int b = blockIdx.x, t = threadIdx.x;
    {
        us4 u = *(const us4*)(hb + ((size_t)b << 10) + t * 4);
        #pragma unroll
        for (int j = 0; j < 4; j++) hf[t * 4 + j] = b2f(u[j]);
    }
    __syncthreads();
    {
        const int c = t & 63, ks = (t >> 6) * 256;
        float s = 0.f;
        #pragma unroll 8
        for (int k = 0; k < 256; k++)
            s += hf[ks + k] * b2f(wAhT[(size_t)(ks + k) * S_LEN + c]);
        part[t >> 6][c] = s;
    }
    __syncthreads();
    if (t < 64) {
        float v = part[0][t] + part[1][t] + part[2][t] + part[3][t]
                + b2f(attnx_t[b * S_LEN + t]);
        float m = v;
        #pragma unroll
        for (int off = 32; off; off >>= 1) m = fmaxf(m, __shfl_xor(m, off));
        float e = __expf(v - m);
        float ss = e;
        #pragma unroll
        for (int off = 32; off; off >>= 1) ss += __shfl_xor(ss, off);
        awl[t] = e / ss;
    }
    __syncthreads();
    const int hq = t * 4;
    float s0 = 0.f, s1 = 0.f, s2 = 0.f, s3 = 0.f;
    #pragma unroll 4
    for (int l = 0; l < S_LEN; l++) {
        us4 u = *(const us4*)(encb + (((size_t)l * BATCH + b) << 10) + hq);
        float w = awl[l];
        s0 += w * b2f(u[0]); s1 += w * b2f(u[1]);
        s2 += w * b2f(u[2]); s3 += w * b2f(u[3]);
    }
    us4 o; o[0] = f2b(s0); o[1] = f2b(s1); o[2] = f2b(s2); o[3] = f2b(s3);
    *(us4*)(ctx + ((size_t)b << 10) + hq) = o;
}

// strided fp32 -> compact bf16 weight convert, 4 elems/thread (cols % 4 == 0)
__global__ void cvt_w4(const float* __restrict__ src, int ld,
                       unsigned short* __restrict__ dst, int rows, int cols)
{
    int idx = blockIdx.x * blockDim.x + threadIdx.x;
    int total4 = rows * cols / 4;
    if (idx >= total4) return;
    int e = idx * 4;
    int r = e / cols, c = e - r * cols;
    const float* s = src + (size_t)r * ld + c;
    us4 o;
    #pragma unroll
    for (int j = 0; j < 4; j++) o[j] = f2b(s[j]);
    *(us4*)(dst + e) = o;
}

// contiguous fp32 -> bf16, 4 elems/thread
__global__ void cvt_plain4(const float* __restrict__ src,
                           unsigned short* __restrict__ dst, int total4)
{
    int idx = blockIdx.x * blockDim.x + threadIdx.x;
    if (idx >= total4) return;
    f32x4 v = *(const f32x4*)(src + (size_t)idx * 4);
    us4 o;
    #pragma unroll
    for (int j = 0; j < 4; j++) o[j] = f2b(v[j]);
    *(us4*)(dst + (size_t)idx * 4) = o;
}

// fp32 [rows, scols] -> bf16 [rows, dcols] zero-padded
__global__ void cvt_pad(const float* __restrict__ src, int scols,
                        unsigned short* __restrict__ dst, int dcols, int total)
{
    int idx = blockIdx.x * blockDim.x + threadIdx.x;
    if (idx >= total) return;
    int r = idx / dcols, c = idx - r * dcols;
    dst[idx] = (c < scols) ? f2b(src[(size_t)r * scols + c]) : (unsigned short)0;
}

// attn_W[:, H:2H] fp32 [64, ld 2048] -> wAhT bf16 [k][c]
__global__ void cvt_attT(const float* __restrict__ attn_W,
                         unsigned short* __restrict__ dst)
{
    int idx = blockIdx.x * blockDim.x + threadIdx.x;
    if (idx >= S_LEN * H_DIM) return;
    int k = idx >> 6, c = idx & 63;
    dst[idx] = f2b(attn_W[(size_t)c * 2 * H_DIM + H_DIM + k]);
}

__global__ void log_softmax1024(float* __restrict__ x)
{
    __shared__ float red[256];
    float* xr = x + (size_t)blockIdx.x * O_DIM;
    int t = threadIdx.x;
    float m = -1e30f;
    for (int i = t; i < O_DIM; i += 256) m = fmaxf(m, xr[i]);
    red[t] = m; __syncthreads();
    for (int s2 = 128; s2 > 0; s2 >>= 1) {
        if (t < s2) red[t] = fmaxf(red[t], red[t + s2]);
        __syncthreads();
    }
    m = red[0];
    __syncthreads();
    float s = 0.f;
    for (int i = t; i < O_DIM; i += 256) s += expf(xr[i] - m);
    red[t] = s; __syncthreads();
    for (int s2 = 128; s2 > 0; s2 >>= 1) {
        if (t < s2) red[t] += red[t + s2];
        __syncthreads();
    }
    float lse = m + logf(red[0]);
    __syncthreads();
    for (int i = t; i < O_DIM; i += 256) xr[i] = xr[i] - lse;
}

// ---------------------------------------------------------------------------
extern "C" void kernel_launch(void* const* d_in, const int* in_sizes, int n_in,
                              void* d_out, int out_size, void* d_ws, size_t ws_size,
                              hipStream_t stream)
{
    const float* input   = (const float*)d_in[0];   // [S,B,IN]
    const float* target  = (const float*)d_in[1];   // [T,B,H]
    const float* enc_Wih = (const float*)d_in[2];
    const float* enc_Whh = (const float*)d_in[3];
    const float* enc_bih = (const float*)d_in[4];
    const float* enc_bhh = (const float*)d_in[5];
    const float* attn_W  = (const float*)d_in[6];   // [S,2H]
    const float* attn_b  = (const float*)d_in[7];
    const float* comb_W  = (const float*)d_in[8];   // [H,2H]
    const float* comb_b  = (const float*)d_in[9];
    const float* dec_Wih = (const float*)d_in[10];
    const float* dec_Whh = (const float*)d_in[11];
    const float* dec_bih = (const float*)d_in[12];
    const float* dec_bhh = (const float*)d_in[13];
    const float* out_W   = (const float*)d_in[14];
    const float* out_b   = (const float*)d_in[15];
    float* out = (float*)d_out;                     // [B,O] fp32

    // ---- workspace layout ----
    char* p = (char*)d_ws;
    auto alloc = [&](size_t bytes) {
        char* r = p; p += (bytes + 255) & ~(size_t)255; return r;
    };
    unsigned short* wWhh  = (unsigned short*)alloc((size_t)H3 * H_DIM * 2);
    unsigned short* wDih  = (unsigned short*)alloc((size_t)H3 * H_DIM * 2);
    unsigned short* wDhh  = (unsigned short*)alloc((size_t)H3 * H_DIM * 2);
    unsigned short* wCc   = (unsigned short*)alloc((size_t)H_DIM * H_DIM * 2);
    unsigned short* wCx   = (unsigned short*)alloc((size_t)H_DIM * H_DIM * 2);
    unsigned short* wO    = (unsigned short*)alloc((size_t)O_DIM * H_DIM * 2);
    unsigned short* wAhT  = (unsigned short*)alloc((size_t)H_DIM * S_LEN * 2);
    unsigned short* wAx   = (unsigned short*)alloc((size_t)S_LEN * H_DIM * 2);
    unsigned short* wIhp  = (unsigned short*)alloc((size_t)H3 * INP * 2);
    unsigned short* xbp   = (unsigned short*)alloc((size_t)S_LEN * BATCH * INP * 2);
    unsigned short* encb  = (unsigned short*)alloc((size_t)S_LEN * BATCH * H_DIM * 2);
    unsigned short* combx = (unsigned short*)alloc((size_t)(T_LEN - 1) * BATCH * H_DIM * 2);
    unsigned short* attnx = (unsigned short*)alloc((size_t)(T_LEN - 1) * BATCH * S_LEN * 2);
    float*          h     = (float*)alloc((size_t)BATCH * H_DIM * 4);
    unsigned short* hbA   = (unsigned short*)alloc((size_t)BATCH * H_DIM * 2);
    unsigned short* hbB   = (unsigned short*)alloc((size_t)BATCH * H_DIM * 2);
    unsigned short* ctx   = (unsigned short*)alloc((size_t)BATCH * H_DIM * 2);
    unsigned short* comb  = (unsigned short*)alloc((size_t)BATCH * H_DIM * 2);
    // targetb overlays encb: consumed (attnx/combx gemms) before encoder
    // writes encb. [32*512, 1024] bf16 = 33.5 MB inside encb's 64 MB.
    unsigned short* targetb = encb;

    const dim3 blk(256);

    hipMemsetAsync(h,   0, (size_t)BATCH * H_DIM * 4, stream);
    hipMemsetAsync(hbA, 0, (size_t)BATCH * H_DIM * 2, stream);

    // ---- one-time converts (all bf16) ----
    cvt_w4<<<(H3 * H_DIM / 4 + 255) / 256, blk, 0, stream>>>(enc_Whh, H_DIM, wWhh, H3, H_DIM);
    cvt_w4<<<(H3 * H_DIM / 4 + 255) / 256, blk, 0, stream>>>(dec_Wih, H_DIM, wDih, H3, H_DIM);
    cvt_w4<<<(H3 * H_DIM / 4 + 255) / 256, blk, 0, stream>>>(dec_Whh, H_DIM, wDhh, H3, H_DIM);
    cvt_w4<<<(H_DIM * H_DIM / 4 + 255) / 256, blk, 0, stream>>>(comb_W + H_DIM, 2 * H_DIM, wCc, H_DIM, H_DIM);
    cvt_w4<<<(H_DIM * H_DIM / 4 + 255) / 256, blk, 0, stream>>>(comb_W, 2 * H_DIM, wCx, H_DIM, H_DIM);
    cvt_w4<<<(O_DIM * H_DIM / 4 + 255) / 256, blk, 0, stream>>>(out_W, H_DIM, wO, O_DIM, H_DIM);
    cvt_w4<<<(S_LEN * H_DIM / 4 + 255) / 256, blk, 0, stream>>>(attn_W, 2 * H_DIM, wAx, S_LEN, H_DIM);
    cvt_attT<<<(S_LEN * H_DIM + 255) / 256, blk, 0, stream>>>(attn_W, wAhT);
    cvt_pad<<<((S_LEN * BATCH * INP) + 255) / 256, blk, 0, stream>>>(
        input, IN_DIM, xbp, INP, S_LEN * BATCH * INP);
    cvt_pad<<<((H3 * INP) + 255) / 256, blk, 0, stream>>>(
        enc_Wih, IN_DIM, wIhp, INP, H3 * INP);
    cvt_plain4<<<((T_LEN * BATCH * H_DIM / 4) + 255) / 256, blk, 0, stream>>>(
        target, targetb, T_LEN * BATCH * H_DIM / 4);

    const int MT = (T_LEN - 1) * BATCH;  // 15872
    // attnx = target @ attn_W[:, :H]^T + attn_b
    gemm_k<64, 64><<<dim3(1, MT / 64), blk, 0, stream>>>(
        targetb, H_DIM, wAx, H_DIM, attn_b,
        nullptr, nullptr, 0, nullptr, attnx, S_LEN, H_DIM, 1 | 32);
    // combx = target @ comb_W[:, :H]^T + comb_b  (64x128 tile, round-4 proven)
    gemm_k<64, 128><<<dim3(H_DIM / 128, MT / 64), blk, 0, stream>>>(
        targetb, H_DIM, wCx, H_DIM, comb_b,
        nullptr, nullptr, 0, nullptr, combx, H_DIM, H_DIM, 1 | 32);

    const dim3 grid_gru(H_DIM / 32, BATCH / 64);   // (32, 8) = 256 blocks
    unsigned short* hcur = hbA;
    unsigned short* hnxt = hbB;

    // ---------------- encoder: one kernel per step ----------------
    for (int s = 0; s < S_LEN; s++) {
        gru_gemm<<<grid_gru, blk, 0, stream>>>(
            xbp + (size_t)s * BATCH * INP, INP, wIhp, INP, INP,
            hcur, wWhh, enc_bih, enc_bhh, h, h, hnxt,
            encb + (size_t)s * BATCH * H_DIM);
        unsigned short* tmp = hcur; hcur = hnxt; hnxt = tmp;
    }

    // ---------------- decoder: three kernels per step ----------------
    for (int t = 0; t < T_LEN - 1; t++) {
        attn_ctx<<<BATCH, blk, 0, stream>>>(
            hcur, wAhT, attnx + (size_t)t * BATCH * S_LEN, encb, ctx);
        gemm_k<32, 64><<<dim3(H_DIM / 64, BATCH / 32), blk, 0, stream>>>(
            ctx, H_DIM, wCc, H_DIM, nullptr,
            nullptr, combx + (size_t)t * BATCH * H_DIM, H_DIM,
            nullptr, comb, H_DIM, H_DIM, 4 | 8 | 32);
        gru_gemm<<<grid_gru, blk, 0, stream>>>(
            comb, H_DIM, wDih, H_DIM, H_DIM,
            hcur, wDhh, dec_bih, dec_bhh, h, h, hnxt, nullptr);
        unsigned short* tmp = hcur; hcur = hnxt; hnxt = tmp;
    }

    // ---------------- output ----------------
    gemm_k<32, 64><<<dim3(O_DIM / 64, BATCH / 32), blk, 0, stream>>>(
        hcur, H_DIM, wO, H_DIM, out_b,
        nullptr, nullptr, 0, out, nullptr, O_DIM, H_DIM, 1 | 16);
    log_softmax1024<<<BATCH, blk, 0, stream>>>(out);
}

// Round 7
// 3782.328 us; speedup vs baseline: 1.1195x; 1.1195x over previous
//
#include <hip/hip_runtime.h>
#include <hip/hip_bf16.h>
#include <math.h>

#define S_LEN 64
#define T_LEN 32
#define BATCH 512
#define IN_DIM 66
#define INP 128         // IN_DIM zero-padded to multiple of 64
#define H_DIM 1024
#define O_DIM 1024
#define H3 3072

typedef __attribute__((ext_vector_type(8))) short short8;
typedef __attribute__((ext_vector_type(4))) float f32x4;
typedef __attribute__((ext_vector_type(4))) unsigned short us4;

__device__ __forceinline__ unsigned short f2b(float f) {
    union { float f; unsigned u; } x; x.f = f;
    unsigned r = x.u + 0x7FFF + ((x.u >> 16) & 1);
    return (unsigned short)(r >> 16);
}
__device__ __forceinline__ float b2f(unsigned short s) {
    union { unsigned u; float f; } x; x.u = ((unsigned)s) << 16;
    return x.f;
}
// async global->LDS, 16B per lane; lds base must be wave-uniform
__device__ __forceinline__ void gll16(const void* g, const void* l) {
    __builtin_amdgcn_global_load_lds(
        (const __attribute__((address_space(1))) unsigned int*)g,
        (__attribute__((address_space(3))) unsigned int*)l, 16, 0, 0);
}

// ---------------------------------------------------------------------------
// MFMA GEMM, bf16: C[M,N] = A@W^T, tile TM x TN. lda/ldw mult of 8, K mult 32.
// flags: 1 bias, 2 add fp32, 4 add bf16, 8 relu, 16 store f32, 32 store bf16
// ---------------------------------------------------------------------------
template<int TM, int TN>
__global__ __launch_bounds__(256) void gemm_k(
    const unsigned short* __restrict__ A, int lda,
    const unsigned short* __restrict__ W, int ldw,
    const float* __restrict__ bias,
    const float* __restrict__ addf, const unsigned short* __restrict__ addb,
    int ldadd,
    float* __restrict__ Cf,
    unsigned short* __restrict__ Cb, int ldc,
    int K, int flags)
{
    constexpr int IF = TM / 16;   // A frags per wave
    constexpr int JF = TN / 64;   // B frags per wave
    constexpr int NW = TN / 4;    // cols per wave
    constexpr int CA = TM * 4;    // 16B chunks in A tile
    constexpr int CW = TN * 4;
    __shared__ __align__(16) unsigned short As[TM * 32];
    __shared__ __align__(16) unsigned short Bs[TN * 32];

    const int bm = blockIdx.y * TM;
    const int bn = blockIdx.x * TN;
    const int t = threadIdx.x;
    const int lane = t & 63;
    const int wv = t >> 6;
    const int ln = lane & 15;
    const int quad = lane >> 4;

    f32x4 acc[IF][JF];
    #pragma unroll
    for (int i = 0; i < IF; i++)
        #pragma unroll
        for (int j = 0; j < JF; j++) {
            f32x4 z = {0.f, 0.f, 0.f, 0.f};
            acc[i][j] = z;
        }

    for (int k0 = 0; k0 < K; k0 += 32) {
        if constexpr (CA >= 256) {
            #pragma unroll
            for (int j = 0; j < CA / 256; j++) {
                int ch = j * 256 + t;
                gll16(A + (size_t)(bm + (ch >> 2)) * lda + k0 + (ch & 3) * 8,
                      (const char*)As + (j * 4 + wv) * 1024);
            }
        } else {
            if (t < CA)
                gll16(A + (size_t)(bm + (t >> 2)) * lda + k0 + (t & 3) * 8,
                      (const char*)As + wv * 1024);
        }
        if constexpr (CW >= 256) {
            #pragma unroll
            for (int j = 0; j < CW / 256; j++) {
                int ch = j * 256 + t;
                gll16(W + (size_t)(bn + (ch >> 2)) * ldw + k0 + (ch & 3) * 8,
                      (const char*)Bs + (j * 4 + wv) * 1024);
            }
        } else {
            if (t < CW)
                gll16(W + (size_t)(bn + (t >> 2)) * ldw + k0 + (t & 3) * 8,
                      (const char*)Bs + wv * 1024);
        }
        __syncthreads();
        short8 af[IF], bf[JF];
        #pragma unroll
        for (int i = 0; i < IF; i++)
            af[i] = *(const short8*)&As[(i * 16 + ln) * 32 + quad * 8];
        #pragma unroll
        for (int j = 0; j < JF; j++)
            bf[j] = *(const short8*)&Bs[(wv * NW + j * 16 + ln) * 32 + quad * 8];
        #pragma unroll
        for (int i = 0; i < IF; i++)
            #pragma unroll
            for (int j = 0; j < JF; j++)
                acc[i][j] = __builtin_amdgcn_mfma_f32_16x16x32_bf16(
                    af[i], bf[j], acc[i][j], 0, 0, 0);
        __syncthreads();
    }

    #pragma unroll
    for (int i = 0; i < IF; i++) {
        #pragma unroll
        for (int j = 0; j < JF; j++) {
            #pragma unroll
            for (int r = 0; r < 4; r++) {
                int m = bm + i * 16 + quad * 4 + r;
                int n = bn + wv * NW + j * 16 + ln;
                float v = acc[i][j][r];
                if (flags & 1) v += bias[n];
                if (flags & 2) v += addf[(size_t)m * ldadd + n];
                if (flags & 4) v += b2f(addb[(size_t)m * ldadd + n]);
                if (flags & 8) v = fmaxf(v, 0.f);
                if (flags & 16) Cf[(size_t)m * ldc + n] = v;
                if (flags & 32) Cb[(size_t)m * ldc + n] = f2b(v);
            }
        }
    }
}

// ---------------------------------------------------------------------------
// GRU step, double-buffered pipeline. Tile 32 batch x 64 cols/gate, BK=64
// staged as two BK=32 subtiles (m97 64B row stride: no bank conflicts, and
// gll16-compatible). Per buffer: A 4 KB + W 24 KB; x2 buffers = 56 KB LDS.
// One barrier per tile: barrier -> issue prefetch(t+1, other buf) ->
// compute(t). The prefetch's L2 latency is covered by compute before the
// next barrier's vmcnt drain.
// ---------------------------------------------------------------------------
__device__ __forceinline__ void gru_issue(
    const unsigned short* __restrict__ A, int lda,
    const unsigned short* __restrict__ W, int ldw, int kb,
    unsigned short* As_b, unsigned short* Ws_b,
    int t, int wv, int bm, int bn)
{
    // A: 256 chunks: sub t>>7, row (t>>2)&31, kchunk t&3
    {
        int s = t >> 7, r = (t >> 2) & 31, c = t & 3;
        gll16(A + (size_t)(bm + r) * lda + kb + s * 32 + c * 8,
              (const char*)As_b + wv * 1024);
    }
    // W: 1536 chunks (512/gate): gate ch>>9; ch2=ch&511: sub ch2>>8,
    // row (ch2>>2)&63, kchunk ch2&3
    #pragma unroll
    for (int j = 0; j < 6; j++) {
        int ch = j * 256 + t;
        int g2 = ch >> 9, ch2 = ch & 511;
        int s = ch2 >> 8, r = (ch2 >> 2) & 63, c = ch2 & 3;
        gll16(W + (size_t)(g2 * H_DIM + bn + r) * ldw + kb + s * 32 + c * 8,
              (const char*)Ws_b + j * 4096 + wv * 1024);
    }
}

__device__ __forceinline__ void gru_compute(
    const unsigned short* As_b, const unsigned short* Ws_b,
    int wv, int ln, int quad,
    f32x4 (&accR)[2], f32x4 (&accZ)[2], f32x4 (&accN)[2])
{
    #pragma unroll
    for (int sub = 0; sub < 2; sub++) {
        short8 a[2], bw[3];
        #pragma unroll
        for (int i = 0; i < 2; i++)
            a[i] = *(const short8*)&As_b[sub * 1024 + (i * 16 + ln) * 32 + quad * 8];
        #pragma unroll
        for (int g = 0; g < 3; g++)
            bw[g] = *(const short8*)&Ws_b[g * 4096 + sub * 2048 + (wv * 16 + ln) * 32 + quad * 8];
        #pragma unroll
        for (int i = 0; i < 2; i++) {
            accR[i] = __builtin_amdgcn_mfma_f32_16x16x32_bf16(a[i], bw[0], accR[i], 0, 0, 0);
            accZ[i] = __builtin_amdgcn_mfma_f32_16x16x32_bf16(a[i], bw[1], accZ[i], 0, 0, 0);
            accN[i] = __builtin_amdgcn_mfma_f32_16x16x32_bf16(a[i], bw[2], accN[i], 0, 0, 0);
        }
    }
}

__global__ __launch_bounds__(256) void gru_gemm(
    const unsigned short* __restrict__ A0, int lda0,
    const unsigned short* __restrict__ W0, int ldw0, int K0,
    const unsigned short* __restrict__ A1,   // hb_in [512,1024]
    const unsigned short* __restrict__ W1,   // Whh   [3072,1024]
    const float* __restrict__ bih, const float* __restrict__ bhh,
    const float* __restrict__ hf_in, float* __restrict__ hf_out,
    unsigned short* __restrict__ hb_out, unsigned short* __restrict__ slot)
{
    __shared__ __align__(16) unsigned short AsB[2][2 * 32 * 32];      //  8 KB
    __shared__ __align__(16) unsigned short WsB[2][3 * 2 * 64 * 32];  // 48 KB
    const int bm = blockIdx.y * 32;
    const int bn = blockIdx.x * 64;
    const int t = threadIdx.x;
    const int lane = t & 63;
    const int wv = t >> 6;
    const int ln = lane & 15;
    const int quad = lane >> 4;

    f32x4 accR[2], accZ[2], accN0[2], accN1[2];
    #pragma unroll
    for (int i = 0; i < 2; i++) {
        f32x4 z = {0.f, 0.f, 0.f, 0.f};
        accR[i] = z; accZ[i] = z; accN0[i] = z; accN1[i] = z;
    }

    const int nx0 = K0 >> 6;          // x-phase tiles
    const int NT = nx0 + 16;          // + h-phase tiles (K=1024)

    gru_issue(A0, lda0, W0, ldw0, 0, AsB[0], WsB[0], t, wv, bm, bn);
    for (int tl = 0; tl < NT; tl++) {
        __syncthreads();              // tile tl resident; prev buf free
        const int nxt = tl + 1;
        if (nxt < NT) {
            if (nxt < nx0)
                gru_issue(A0, lda0, W0, ldw0, nxt << 6,
                          AsB[nxt & 1], WsB[nxt & 1], t, wv, bm, bn);
            else
                gru_issue(A1, H_DIM, W1, H_DIM, (nxt - nx0) << 6,
                          AsB[nxt & 1], WsB[nxt & 1], t, wv, bm, bn);
        }
        if (tl < nx0)
            gru_compute(AsB[tl & 1], WsB[tl & 1], wv, ln, quad,
                        accR, accZ, accN0);
        else
            gru_compute(AsB[tl & 1], WsB[tl & 1], wv, ln, quad,
                        accR, accZ, accN1);
    }

    const int n = bn + wv * 16 + ln;
    const float br = bih[n] + bhh[n];
    const float bz = bih[H_DIM + n] + bhh[H_DIM + n];
    const float bi_n = bih[2 * H_DIM + n];
    const float bh_n = bhh[2 * H_DIM + n];
    #pragma unroll
    for (int i = 0; i < 2; i++) {
        #pragma unroll
        for (int r = 0; r < 4; r++) {
            const int m = bm + i * 16 + quad * 4 + r;
            const size_t idx = (size_t)m * H_DIM + n;
            float rg = 1.f / (1.f + __expf(-(accR[i][r] + br)));
            float zg = 1.f / (1.f + __expf(-(accZ[i][r] + bz)));
            float av = accN0[i][r] + bi_n + rg * (accN1[i][r] + bh_n);
            float e2 = __expf(-2.f * fabsf(av));
            float th = (1.f - e2) / (1.f + e2);
            th = av < 0.f ? -th : th;
            float o = (1.f - zg) * th + zg * hf_in[idx];
            hf_out[idx] = o;
            unsigned short ob = f2b(o);
            hb_out[idx] = ob;
            if (slot) slot[idx] = ob;
        }
    }
}

// ---------------------------------------------------------------------------
// Fused attention: one block per batch row. scores = h.wAhT + attnx (bf16),
// softmax over 64, then ctx[b,:] = sum_l aw[l] * enc[l,b,:]. 512 blocks.
// ---------------------------------------------------------------------------
__global__ __launch_bounds__(256) void attn_ctx(
    const unsigned short* __restrict__ hb,     // [512,1024] bf16
    const unsigned short* __restrict__ wAhT,   // [1024][64] bf16 (k-major)
    const unsigned short* __restrict__ attnx_t,// [512,64] bf16 (incl bias)
    const unsigned short* __restrict__ encb,   // [64,512,1024] bf16
    unsigned short* __restrict__ ctx)          // [512,1024] bf16
{
    __shared__ float hf[H_DIM];
    __shared__ float part[4][S_LEN];
    __shared__ float awl[S_LEN];
    const int b = blockIdx.x, t = threadIdx.x;
    {
        us4 u = *(const us4*)(hb + ((size_t)b << 10) + t * 4);
        #pragma unroll
        for (int j = 0; j < 4; j++) hf[t * 4 + j] = b2f(u[j]);
    }
    __syncthreads();
    {
        const int c = t & 63, ks = (t >> 6) * 256;
        float s = 0.f;
        #pragma unroll 8
        for (int k = 0; k < 256; k++)
            s += hf[ks + k] * b2f(wAhT[(size_t)(ks + k) * S_LEN + c]);
        part[t >> 6][c] = s;
    }
    __syncthreads();
    if (t < 64) {
        float v = part[0][t] + part[1][t] + part[2][t] + part[3][t]
                + b2f(attnx_t[b * S_LEN + t]);
        float m = v;
        #pragma unroll
        for (int off = 32; off; off >>= 1) m = fmaxf(m, __shfl_xor(m, off));
        float e = __expf(v - m);
        float ss = e;
        #pragma unroll
        for (int off = 32; off; off >>= 1) ss += __shfl_xor(ss, off);
        awl[t] = e / ss;
    }
    __syncthreads();
    const int hq = t * 4;
    float s0 = 0.f, s1 = 0.f, s2 = 0.f, s3 = 0.f;
    #pragma unroll 4
    for (int l = 0; l < S_LEN; l++) {
        us4 u = *(const us4*)(encb + (((size_t)l * BATCH + b) << 10) + hq);
        float w = awl[l];
        s0 += w * b2f(u[0]); s1 += w * b2f(u[1]);
        s2 += w * b2f(u[2]); s3 += w * b2f(u[3]);
    }
    us4 o; o[0] = f2b(s0); o[1] = f2b(s1); o[2] = f2b(s2); o[3] = f2b(s3);
    *(us4*)(ctx + ((size_t)b << 10) + hq) = o;
}

// strided fp32 -> compact bf16 weight convert, 4 elems/thread (cols % 4 == 0)
__global__ void cvt_w4(const float* __restrict__ src, int ld,
                       unsigned short* __restrict__ dst, int rows, int cols)
{
    int idx = blockIdx.x * blockDim.x + threadIdx.x;
    int total4 = rows * cols / 4;
    if (idx >= total4) return;
    int e = idx * 4;
    int r = e / cols, c = e - r * cols;
    const float* s = src + (size_t)r * ld + c;
    us4 o;
    #pragma unroll
    for (int j = 0; j < 4; j++) o[j] = f2b(s[j]);
    *(us4*)(dst + e) = o;
}

// contiguous fp32 -> bf16, 4 elems/thread
__global__ void cvt_plain4(const float* __restrict__ src,
                           unsigned short* __restrict__ dst, int total4)
{
    int idx = blockIdx.x * blockDim.x + threadIdx.x;
    if (idx >= total4) return;
    f32x4 v = *(const f32x4*)(src + (size_t)idx * 4);
    us4 o;
    #pragma unroll
    for (int j = 0; j < 4; j++) o[j] = f2b(v[j]);
    *(us4*)(dst + (size_t)idx * 4) = o;
}

// fp32 [rows, scols] -> bf16 [rows, dcols] zero-padded
__global__ void cvt_pad(const float* __restrict__ src, int scols,
                        unsigned short* __restrict__ dst, int dcols, int total)
{
    int idx = blockIdx.x * blockDim.x + threadIdx.x;
    if (idx >= total) return;
    int r = idx / dcols, c = idx - r * dcols;
    dst[idx] = (c < scols) ? f2b(src[(size_t)r * scols + c]) : (unsigned short)0;
}

// attn_W[:, H:2H] fp32 [64, ld 2048] -> wAhT bf16 [k][c]
__global__ void cvt_attT(const float* __restrict__ attn_W,
                         unsigned short* __restrict__ dst)
{
    int idx = blockIdx.x * blockDim.x + threadIdx.x;
    if (idx >= S_LEN * H_DIM) return;
    int k = idx >> 6, c = idx & 63;
    dst[idx] = f2b(attn_W[(size_t)c * 2 * H_DIM + H_DIM + k]);
}

__global__ void log_softmax1024(float* __restrict__ x)
{
    __shared__ float red[256];
    float* xr = x + (size_t)blockIdx.x * O_DIM;
    int t = threadIdx.x;
    float m = -1e30f;
    for (int i = t; i < O_DIM; i += 256) m = fmaxf(m, xr[i]);
    red[t] = m; __syncthreads();
    for (int s2 = 128; s2 > 0; s2 >>= 1) {
        if (t < s2) red[t] = fmaxf(red[t], red[t + s2]);
        __syncthreads();
    }
    m = red[0];
    __syncthreads();
    float s = 0.f;
    for (int i = t; i < O_DIM; i += 256) s += expf(xr[i] - m);
    red[t] = s; __syncthreads();
    for (int s2 = 128; s2 > 0; s2 >>= 1) {
        if (t < s2) red[t] += red[t + s2];
        __syncthreads();
    }
    float lse = m + logf(red[0]);
    __syncthreads();
    for (int i = t; i < O_DIM; i += 256) xr[i] = xr[i] - lse;
}

// ---------------------------------------------------------------------------
extern "C" void kernel_launch(void* const* d_in, const int* in_sizes, int n_in,
                              void* d_out, int out_size, void* d_ws, size_t ws_size,
                              hipStream_t stream)
{
    const float* input   = (const float*)d_in[0];   // [S,B,IN]
    const float* target  = (const float*)d_in[1];   // [T,B,H]
    const float* enc_Wih = (const float*)d_in[2];
    const float* enc_Whh = (const float*)d_in[3];
    const float* enc_bih = (const float*)d_in[4];
    const float* enc_bhh = (const float*)d_in[5];
    const float* attn_W  = (const float*)d_in[6];   // [S,2H]
    const float* attn_b  = (const float*)d_in[7];
    const float* comb_W  = (const float*)d_in[8];   // [H,2H]
    const float* comb_b  = (const float*)d_in[9];
    const float* dec_Wih = (const float*)d_in[10];
    const float* dec_Whh = (const float*)d_in[11];
    const float* dec_bih = (const float*)d_in[12];
    const float* dec_bhh = (const float*)d_in[13];
    const float* out_W   = (const float*)d_in[14];
    const float* out_b   = (const float*)d_in[15];
    float* out = (float*)d_out;                     // [B,O] fp32

    // ---- workspace layout ----
    char* p = (char*)d_ws;
    auto alloc = [&](size_t bytes) {
        char* r = p; p += (bytes + 255) & ~(size_t)255; return r;
    };
    unsigned short* wWhh  = (unsigned short*)alloc((size_t)H3 * H_DIM * 2);
    unsigned short* wDih  = (unsigned short*)alloc((size_t)H3 * H_DIM * 2);
    unsigned short* wDhh  = (unsigned short*)alloc((size_t)H3 * H_DIM * 2);
    unsigned short* wCc   = (unsigned short*)alloc((size_t)H_DIM * H_DIM * 2);
    unsigned short* wCx   = (unsigned short*)alloc((size_t)H_DIM * H_DIM * 2);
    unsigned short* wO    = (unsigned short*)alloc((size_t)O_DIM * H_DIM * 2);
    unsigned short* wAhT  = (unsigned short*)alloc((size_t)H_DIM * S_LEN * 2);
    unsigned short* wAx   = (unsigned short*)alloc((size_t)S_LEN * H_DIM * 2);
    unsigned short* wIhp  = (unsigned short*)alloc((size_t)H3 * INP * 2);
    unsigned short* xbp   = (unsigned short*)alloc((size_t)S_LEN * BATCH * INP * 2);
    unsigned short* encb  = (unsigned short*)alloc((size_t)S_LEN * BATCH * H_DIM * 2);
    unsigned short* combx = (unsigned short*)alloc((size_t)(T_LEN - 1) * BATCH * H_DIM * 2);
    unsigned short* attnx = (unsigned short*)alloc((size_t)(T_LEN - 1) * BATCH * S_LEN * 2);
    float*          h     = (float*)alloc((size_t)BATCH * H_DIM * 4);
    unsigned short* hbA   = (unsigned short*)alloc((size_t)BATCH * H_DIM * 2);
    unsigned short* hbB   = (unsigned short*)alloc((size_t)BATCH * H_DIM * 2);
    unsigned short* ctx   = (unsigned short*)alloc((size_t)BATCH * H_DIM * 2);
    unsigned short* comb  = (unsigned short*)alloc((size_t)BATCH * H_DIM * 2);
    // targetb overlays encb: consumed (attnx/combx gemms) before encoder
    // writes encb. [32*512, 1024] bf16 = 33.5 MB inside encb's 64 MB.
    unsigned short* targetb = encb;

    const dim3 blk(256);

    hipMemsetAsync(h,   0, (size_t)BATCH * H_DIM * 4, stream);
    hipMemsetAsync(hbA, 0, (size_t)BATCH * H_DIM * 2, stream);

    // ---- one-time converts (all bf16) ----
    cvt_w4<<<(H3 * H_DIM / 4 + 255) / 256, blk, 0, stream>>>(enc_Whh, H_DIM, wWhh, H3, H_DIM);
    cvt_w4<<<(H3 * H_DIM / 4 + 255) / 256, blk, 0, stream>>>(dec_Wih, H_DIM, wDih, H3, H_DIM);
    cvt_w4<<<(H3 * H_DIM / 4 + 255) / 256, blk, 0, stream>>>(dec_Whh, H_DIM, wDhh, H3, H_DIM);
    cvt_w4<<<(H_DIM * H_DIM / 4 + 255) / 256, blk, 0, stream>>>(comb_W + H_DIM, 2 * H_DIM, wCc, H_DIM, H_DIM);
    cvt_w4<<<(H_DIM * H_DIM / 4 + 255) / 256, blk, 0, stream>>>(comb_W, 2 * H_DIM, wCx, H_DIM, H_DIM);
    cvt_w4<<<(O_DIM * H_DIM / 4 + 255) / 256, blk, 0, stream>>>(out_W, H_DIM, wO, O_DIM, H_DIM);
    cvt_w4<<<(S_LEN * H_DIM / 4 + 255) / 256, blk, 0, stream>>>(attn_W, 2 * H_DIM, wAx, S_LEN, H_DIM);
    cvt_attT<<<(S_LEN * H_DIM + 255) / 256, blk, 0, stream>>>(attn_W, wAhT);
    cvt_pad<<<((S_LEN * BATCH * INP) + 255) / 256, blk, 0, stream>>>(
        input, IN_DIM, xbp, INP, S_LEN * BATCH * INP);
    cvt_pad<<<((H3 * INP) + 255) / 256, blk, 0, stream>>>(
        enc_Wih, IN_DIM, wIhp, INP, H3 * INP);
    cvt_plain4<<<((T_LEN * BATCH * H_DIM / 4) + 255) / 256, blk, 0, stream>>>(
        target, targetb, T_LEN * BATCH * H_DIM / 4);

    const int MT = (T_LEN - 1) * BATCH;  // 15872
    // attnx = target @ attn_W[:, :H]^T + attn_b
    gemm_k<64, 64><<<dim3(1, MT / 64), blk, 0, stream>>>(
        targetb, H_DIM, wAx, H_DIM, attn_b,
        nullptr, nullptr, 0, nullptr, attnx, S_LEN, H_DIM, 1 | 32);
    // combx = target @ comb_W[:, :H]^T + comb_b
    gemm_k<64, 128><<<dim3(H_DIM / 128, MT / 64), blk, 0, stream>>>(
        targetb, H_DIM, wCx, H_DIM, comb_b,
        nullptr, nullptr, 0, nullptr, combx, H_DIM, H_DIM, 1 | 32);

    const dim3 grid_gru(H_DIM / 64, BATCH / 32);   // (16, 16) = 256 blocks
    unsigned short* hcur = hbA;
    unsigned short* hnxt = hbB;

    // ---------------- encoder: one kernel per step ----------------
    for (int s = 0; s < S_LEN; s++) {
        gru_gemm<<<grid_gru, blk, 0, stream>>>(
            xbp + (size_t)s * BATCH * INP, INP, wIhp, INP, INP,
            hcur, wWhh, enc_bih, enc_bhh, h, h, hnxt,
            encb + (size_t)s * BATCH * H_DIM);
        unsigned short* tmp = hcur; hcur = hnxt; hnxt = tmp;
    }

    // ---------------- decoder: three kernels per step ----------------
    for (int t = 0; t < T_LEN - 1; t++) {
        attn_ctx<<<BATCH, blk, 0, stream>>>(
            hcur, wAhT, attnx + (size_t)t * BATCH * S_LEN, encb, ctx);
        gemm_k<32, 64><<<dim3(H_DIM / 64, BATCH / 32), blk, 0, stream>>>(
            ctx, H_DIM, wCc, H_DIM, nullptr,
            nullptr, combx + (size_t)t * BATCH * H_DIM, H_DIM,
            nullptr, comb, H_DIM, H_DIM, 4 | 8 | 32);
        gru_gemm<<<grid_gru, blk, 0, stream>>>(
            comb, H_DIM, wDih, H_DIM, H_DIM,
            hcur, wDhh, dec_bih, dec_bhh, h, h, hnxt, nullptr);
        unsigned short* tmp = hcur; hcur = hnxt; hnxt = tmp;
    }

    // ---------------- output ----------------
    gemm_k<32, 64><<<dim3(O_DIM / 64, BATCH / 32), blk, 0, stream>>>(
        hcur, H_DIM, wO, H_DIM, out_b,
        nullptr, nullptr, 0, out, nullptr, O_DIM, H_DIM, 1 | 16);
    log_softmax1024<<<BATCH, blk, 0, stream>>>(out);
}